// Round 7
// baseline (1022.166 us; speedup 1.0000x reference)
//
#include <hip/hip_runtime.h>

#define S_   2048
#define DM_  1024
#define NH_  16
#define HD_  64
#define KDIM 1024
#define QB_  128

typedef __attribute__((ext_vector_type(8))) short  shortx8;
typedef __attribute__((ext_vector_type(4))) float  floatx4;

#define AS1 __attribute__((address_space(1)))
#define AS3 __attribute__((address_space(3)))

__device__ __forceinline__ unsigned short f2bf(float f) {
  unsigned u = __float_as_uint(f);
  u += 0x7FFFu + ((u >> 16) & 1u);
  return (unsigned short)(u >> 16);
}

__device__ __forceinline__ void gld_lds16(const void* g, unsigned short* l) {
  __builtin_amdgcn_global_load_lds((const AS1 void*)g, (AS3 void*)l, 16, 0, 0);
}

// ---------------- convert X,W -> bf16 (once; removes VALU staging from gemm) ----------------
__global__ __launch_bounds__(256) void convert_xw(const void* __restrict__ Xv,
                                                  const void* __restrict__ Wv,
                                                  unsigned short* __restrict__ Xb,
                                                  unsigned short* __restrict__ Wb)
{
  __shared__ int sx;
  const int tid = threadIdx.x, lane = tid & 63;
  if (tid == 0) sx = 0;
  __syncthreads();
  {
    unsigned xv = ((const unsigned*)Xv)[tid];
    unsigned b1 = (xv >> 8) & 0x7Fu;
    bool pb = (b1 >= 0x32u && b1 <= 0x41u);
    unsigned long long bal = __ballot(pb);
    if (lane == 0) atomicAdd(&sx, (int)__popcll(bal));
  }
  __syncthreads();
  const bool xbf = sx > 128;

  const size_t GX = (size_t)4096*1024/8;          // X groups of 8 elems
  const size_t GT = GX + (size_t)3072*1024/8;     // + W groups
  for (size_t g = (size_t)blockIdx.x*256 + tid; g < GT; g += (size_t)gridDim.x*256) {
    const bool isX = g < GX;
    const size_t e = (isX ? g : g - GX) * 8;
    const void* src = isX ? Xv : Wv;
    unsigned short* dst = isX ? Xb : Wb;
    if (xbf) {
      *(uint4*)(dst + e) = *(const uint4*)((const unsigned short*)src + e);
    } else {
      float4 a = *(const float4*)((const float*)src + e);
      float4 b = *(const float4*)((const float*)src + e + 4);
      ushort4 u0{f2bf(a.x), f2bf(a.y), f2bf(a.z), f2bf(a.w)};
      ushort4 u1{f2bf(b.x), f2bf(b.y), f2bf(b.z), f2bf(b.w)};
      *(ushort4*)(dst + e)     = u0;
      *(ushort4*)(dst + e + 4) = u1;
    }
  }
}

// ---------------- QKV projection GEMM (pure m97) ----------------
// C[m][n] = sum_k Xb[m][k]*Wb[n][k]; writes Qg/Kg [b][h][s][d] (Q pre-scaled) and Vt [b][h][d][s].
__global__ __launch_bounds__(256) void qkv_gemm(const unsigned short* __restrict__ Xb,
                                                const unsigned short* __restrict__ Wb,
                                                unsigned short* __restrict__ Qg,
                                                unsigned short* __restrict__ Kg,
                                                unsigned short* __restrict__ Vt)
{
  __shared__ unsigned short lA[128*64];
  __shared__ unsigned short lB[128*64];
  const int tid  = threadIdx.x;
  const int wid  = tid >> 6,  lane = tid & 63;
  const int quad = lane >> 4, l16  = lane & 15;
  const int bm = blockIdx.x, bn = blockIdx.y;
  const int wM = (wid >> 1) * 64, wN = (wid & 1) * 64;

  floatx4 acc[4][4] = {};

  for (int kt = 0; kt < KDIM; kt += 64) {
    __syncthreads();
    #pragma unroll
    for (int p = 0; p < 4; ++p) {
      int chunk = p*256 + tid;
      int r = chunk >> 3, c = chunk & 7;
      gld_lds16(Xb + (size_t)(bm*128 + r)*KDIM + kt + c*8, lA + chunk*8);
    }
    #pragma unroll
    for (int p = 0; p < 4; ++p) {
      int chunk = p*256 + tid;
      int r = chunk >> 3, c = chunk & 7;
      gld_lds16(Wb + (size_t)(bn*128 + r)*KDIM + kt + c*8, lB + chunk*8);
    }
    __syncthreads();

    #pragma unroll
    for (int ks = 0; ks < 2; ++ks) {
      shortx8 af[4], bfr[4];
      #pragma unroll
      for (int mi = 0; mi < 4; ++mi)
        af[mi] = *(const shortx8*)(lA + (wM + mi*16 + l16)*64 + ks*32 + quad*8);
      #pragma unroll
      for (int ni = 0; ni < 4; ++ni)
        bfr[ni] = *(const shortx8*)(lB + (wN + ni*16 + l16)*64 + ks*32 + quad*8);
      #pragma unroll
      for (int mi = 0; mi < 4; ++mi)
        #pragma unroll
        for (int ni = 0; ni < 4; ++ni)
          acc[mi][ni] = __builtin_amdgcn_mfma_f32_16x16x32_bf16(af[mi], bfr[ni], acc[mi][ni], 0, 0, 0);
    }
  }

  if (bn < 8) {
    #pragma unroll
    for (int mi = 0; mi < 4; ++mi)
      #pragma unroll
      for (int ni = 0; ni < 4; ++ni)
        #pragma unroll
        for (int r = 0; r < 4; ++r) {
          int m = bm*128 + wM + mi*16 + quad*4 + r;
          int n = bn*128 + wN + ni*16 + l16;
          int b = m >> 11, q = m & 2047, h = n >> 6, d = n & 63;
          Qg[(((size_t)(b*NH_ + h))*S_ + q)*HD_ + d] = f2bf(acc[mi][ni][r] * 0.125f);
        }
  } else if (bn < 16) {
    #pragma unroll
    for (int mi = 0; mi < 4; ++mi)
      #pragma unroll
      for (int ni = 0; ni < 4; ++ni)
        #pragma unroll
        for (int r = 0; r < 4; ++r) {
          int m = bm*128 + wM + mi*16 + quad*4 + r;
          int n = bn*128 + wN + ni*16 + l16 - 1024;
          int b = m >> 11, t = m & 2047, h = n >> 6, d = n & 63;
          Kg[(((size_t)(b*NH_ + h))*S_ + t)*HD_ + d] = f2bf(acc[mi][ni][r]);
        }
  } else {
    #pragma unroll
    for (int mi = 0; mi < 4; ++mi)
      #pragma unroll
      for (int ni = 0; ni < 4; ++ni) {
        int m0 = bm*128 + wM + mi*16 + quad*4;
        int n  = bn*128 + wN + ni*16 + l16 - 2048;
        int b = m0 >> 11, t = m0 & 2047, h = n >> 6, d = n & 63;
        ushort4 u;
        u.x = f2bf(acc[mi][ni][0]); u.y = f2bf(acc[mi][ni][1]);
        u.z = f2bf(acc[mi][ni][2]); u.w = f2bf(acc[mi][ni][3]);
        *(ushort4*)(Vt + (((size_t)(b*NH_ + h))*HD_ + d)*S_ + t) = u;
      }
  }
}

// ---------------- fused masked flash attention: raw mask, shared K/V frags ----------------
__global__ __launch_bounds__(256, 3) void attn_kernel(const unsigned short* __restrict__ Qg,
                                                      const unsigned short* __restrict__ Kg,
                                                      const unsigned short* __restrict__ Vt,
                                                      const void* __restrict__ maskp,
                                                      const void* __restrict__ xg,
                                                      void* __restrict__ outv)
{
  __shared__ unsigned short lQ[QB_*HD_];     // 16 KB; reused as per-wave P after qf extraction
  __shared__ unsigned short lK[2][64*HD_];   // 16 KB dbuf
  __shared__ unsigned short lVt[2][HD_*64];  // 16 KB dbuf
  __shared__ int sdet[3];

  const int tid  = threadIdx.x;
  const int wid  = tid >> 6,  lane = tid & 63;
  const int quad = lane >> 4, l16  = lane & 15;
  const int qb = blockIdx.x * QB_;
  const int h  = blockIdx.y, b = blockIdx.z;
  const int bh = b*NH_ + h;

  if (tid < 3) sdet[tid] = (tid == 2) ? 0 : 1;
  __syncthreads();
  {
    unsigned mv = ((const unsigned*)maskp)[tid];
    bool w4 = (mv <= 1u) || (mv == 0x3F800000u);           // i32 / f32-bits {0,1}
    unsigned lo = mv & 0xFFFFu, hi = mv >> 16;
    bool w2 = ((lo==0u)||(lo==0x3F80u)) && ((hi==0u)||(hi==0x3F80u));
    unsigned xv = ((const unsigned*)xg)[tid];
    unsigned b1 = (xv >> 8) & 0x7Fu;
    bool pb = (b1 >= 0x32u && b1 <= 0x41u);
    unsigned long long B4 = __ballot(w4), B2 = __ballot(w2), BX = __ballot(pb);
    if (lane == 0) {
      if (~B4) atomicAnd(&sdet[0], 0);
      if (~B2) atomicAnd(&sdet[1], 0);
      atomicAdd(&sdet[2], (int)__popcll(BX));
    }
  }

  #pragma unroll
  for (int p = 0; p < 4; ++p) {
    int chunk = p*256 + tid;
    gld_lds16(Qg + ((size_t)bh*S_ + qb)*HD_ + chunk*8, lQ + chunk*8);
  }

  auto stage = [&](int t0, int buf) {
    #pragma unroll
    for (int p = 0; p < 2; ++p) {
      int chunk = p*256 + tid;
      gld_lds16(Kg + ((size_t)bh*S_ + t0)*HD_ + chunk*8, lK[buf] + chunk*8);
    }
    #pragma unroll
    for (int p = 0; p < 2; ++p) {
      int chunk = p*256 + tid;
      int r = chunk >> 3, c = chunk & 7;
      gld_lds16(Vt + ((size_t)bh*HD_ + r)*S_ + t0 + c*8, lVt[buf] + chunk*8);
    }
  };

  size_t mrow[2][4];
  #pragma unroll
  for (int qh = 0; qh < 2; ++qh)
    #pragma unroll
    for (int r = 0; r < 4; ++r) {
      int q = qb + wid*32 + qh*16 + quad*4 + r;
      mrow[qh][r] = (((size_t)b*S_ + q)*NH_ + h)*S_ + l16;
    }

  stage(0, 0);
  __syncthreads();
  const int esz = sdet[0] ? 4 : (sdet[1] ? 2 : 1);
  const int obf = sdet[2] > 128;

  // raw mask loads for one tile (32 values/lane), elem-size dispatched
  auto loadraw = [&](int t0, unsigned (*mz)[4][4]) {
    if (esz == 4) {
      const unsigned* mp = (const unsigned*)maskp;
      #pragma unroll
      for (int qh = 0; qh < 2; ++qh)
        #pragma unroll
        for (int r = 0; r < 4; ++r)
          #pragma unroll
          for (int tile = 0; tile < 4; ++tile) mz[qh][r][tile] = mp[mrow[qh][r] + t0 + tile*16];
    } else if (esz == 2) {
      const unsigned short* mp = (const unsigned short*)maskp;
      #pragma unroll
      for (int qh = 0; qh < 2; ++qh)
        #pragma unroll
        for (int r = 0; r < 4; ++r)
          #pragma unroll
          for (int tile = 0; tile < 4; ++tile) mz[qh][r][tile] = mp[mrow[qh][r] + t0 + tile*16];
    } else {
      const unsigned char* mp = (const unsigned char*)maskp;
      #pragma unroll
      for (int qh = 0; qh < 2; ++qh)
        #pragma unroll
        for (int r = 0; r < 4; ++r)
          #pragma unroll
          for (int tile = 0; tile < 4; ++tile) mz[qh][r][tile] = mp[mrow[qh][r] + t0 + tile*16];
    }
  };

  shortx8 qf[2][2];
  #pragma unroll
  for (int qh = 0; qh < 2; ++qh)
    #pragma unroll
    for (int ks = 0; ks < 2; ++ks)
      qf[qh][ks] = *(const shortx8*)(lQ + (wid*32 + qh*16 + l16)*HD_ + ks*32 + quad*8);

  floatx4 acc[2][4] = {};
  float lsum[2][4] = {};
  unsigned short* lPw = lQ + wid*2048;   // this wave's 32x64 P region (its own Q rows, now dead)

  unsigned mc = 0;
  {
    unsigned m0[2][4][4];
    loadraw(0, m0);
    #pragma unroll
    for (int qh = 0; qh < 2; ++qh)
      #pragma unroll
      for (int r = 0; r < 4; ++r)
        #pragma unroll
        for (int tile = 0; tile < 4; ++tile)
          mc |= (m0[qh][r][tile] != 0u ? 1u : 0u) << (qh*16 + r*4 + tile);
  }

  for (int t0 = 0; t0 < S_; t0 += 64) {
    const int cur = (t0 >> 6) & 1;
    unsigned mraw[2][4][4];
    const bool more = (t0 + 64 < S_);
    if (more) {
      stage(t0 + 64, cur ^ 1);
      loadraw(t0 + 64, mraw);
    }

    // S = Q K^T — K fragment shared across both qh halves
    floatx4 sc[2][4] = {};
    #pragma unroll
    for (int tile = 0; tile < 4; ++tile)
      #pragma unroll
      for (int ks = 0; ks < 2; ++ks) {
        shortx8 kf = *(const shortx8*)(lK[cur] + (tile*16 + l16)*64 + ks*32 + quad*8);
        sc[0][tile] = __builtin_amdgcn_mfma_f32_16x16x32_bf16(qf[0][ks], kf, sc[0][tile], 0, 0, 0);
        sc[1][tile] = __builtin_amdgcn_mfma_f32_16x16x32_bf16(qf[1][ks], kf, sc[1][tile], 0, 0, 0);
      }

    // max-free masked softmax; P into per-wave LDS (xor-swizzled)
    #pragma unroll
    for (int qh = 0; qh < 2; ++qh)
      #pragma unroll
      for (int r = 0; r < 4; ++r)
        #pragma unroll
        for (int tile = 0; tile < 4; ++tile) {
          float e = __expf(sc[qh][tile][r]);
          e = (mc & (1u << (qh*16 + r*4 + tile))) ? e : 0.f;
          lsum[qh][r] += e;
          int row = qh*16 + quad*4 + r;
          int col = tile*16 + l16;
          lPw[(row << 6) + (((col >> 3) ^ (row & 7)) << 3) + (col & 7)] = f2bf(e);
        }

    // P·V — V fragment shared across both qh halves
    shortx8 pa[2][2];
    #pragma unroll
    for (int qh = 0; qh < 2; ++qh)
      #pragma unroll
      for (int ks = 0; ks < 2; ++ks) {
        int prow = qh*16 + l16;
        pa[qh][ks] = *(const shortx8*)(lPw + (prow << 6) + (((ks*4 + quad) ^ (prow & 7)) << 3));
      }
    #pragma unroll
    for (int ks = 0; ks < 2; ++ks)
      #pragma unroll
      for (int d = 0; d < 4; ++d) {
        shortx8 vb = *(const shortx8*)(lVt[cur] + (d*16 + l16)*64 + ks*32 + quad*8);
        acc[0][d] = __builtin_amdgcn_mfma_f32_16x16x32_bf16(pa[0][ks], vb, acc[0][d], 0, 0, 0);
        acc[1][d] = __builtin_amdgcn_mfma_f32_16x16x32_bf16(pa[1][ks], vb, acc[1][d], 0, 0, 0);
      }

    unsigned mcn = 0;
    if (more) {
      #pragma unroll
      for (int qh = 0; qh < 2; ++qh)
        #pragma unroll
        for (int r = 0; r < 4; ++r)
          #pragma unroll
          for (int tile = 0; tile < 4; ++tile)
            mcn |= (mraw[qh][r][tile] != 0u ? 1u : 0u) << (qh*16 + r*4 + tile);
    }
    __syncthreads();   // drains next-tile staging (a full compute phase old)
    mc = mcn;
  }

  float rinv[2][4];
  #pragma unroll
  for (int qh = 0; qh < 2; ++qh)
    #pragma unroll
    for (int r = 0; r < 4; ++r) {
      float l = lsum[qh][r];
      #pragma unroll
      for (int o = 1; o < 16; o <<= 1) l += __shfl_xor(l, o);
      rinv[qh][r] = 1.f / l;
    }

  #pragma unroll
  for (int qh = 0; qh < 2; ++qh)
    #pragma unroll
    for (int d = 0; d < 4; ++d)
      #pragma unroll
      for (int r = 0; r < 4; ++r) {
        int q = qb + wid*32 + qh*16 + quad*4 + r;
        size_t oi = ((size_t)b*S_ + q)*DM_ + h*HD_ + d*16 + l16;
        float v = acc[qh][d][r] * rinv[qh][r];
        if (obf) ((unsigned short*)outv)[oi] = f2bf(v);
        else     ((float*)outv)[oi]          = v;
      }
}

extern "C" void kernel_launch(void* const* d_in, const int* in_sizes, int n_in,
                              void* d_out, int out_size, void* d_ws, size_t ws_size,
                              hipStream_t stream) {
  (void)in_sizes; (void)n_in; (void)out_size; (void)ws_size;
  const void* X    = d_in[0];
  const void* W    = d_in[1];
  const void* mask = d_in[2];
  const size_t SEG = (size_t)2*NH_*S_*HD_*2;  // 8.39 MB per Q/K/V tensor
  unsigned short* Qg = (unsigned short*)((char*)d_ws + 256);
  unsigned short* Kg = (unsigned short*)((char*)d_ws + 256 + SEG);
  unsigned short* Vt = (unsigned short*)((char*)d_ws + 256 + 2*SEG);
  unsigned short* Xb = (unsigned short*)((char*)d_ws + 256 + 3*SEG);   // 8.39 MB
  unsigned short* Wb = Xb + (size_t)4096*1024;                          // 6.29 MB

  convert_xw<<<512, 256, 0, stream>>>(X, W, Xb, Wb);
  qkv_gemm<<<dim3(32, 24), 256, 0, stream>>>(Xb, Wb, Qg, Kg, Vt);
  attn_kernel<<<dim3(S_/QB_, NH_, 2), 256, 0, stream>>>(Qg, Kg, Vt, mask, X, d_out);
}

// Round 8
// 775.258 us; speedup vs baseline: 1.3185x; 1.3185x over previous
//
#include <hip/hip_runtime.h>

#define S_   2048
#define DM_  1024
#define NH_  16
#define HD_  64
#define KDIM 1024
#define QB_  64

typedef __attribute__((ext_vector_type(8))) short  shortx8;
typedef __attribute__((ext_vector_type(4))) float  floatx4;

#define AS1 __attribute__((address_space(1)))
#define AS3 __attribute__((address_space(3)))

__device__ __forceinline__ unsigned short f2bf(float f) {
  unsigned u = __float_as_uint(f);
  u += 0x7FFFu + ((u >> 16) & 1u);
  return (unsigned short)(u >> 16);
}

__device__ __forceinline__ void gld_lds16(const void* g, unsigned short* l) {
  __builtin_amdgcn_global_load_lds((const AS1 void*)g, (AS3 void*)l, 16, 0, 0);
}

// ---------------- convert X,W -> bf16 (once; removes VALU staging from gemm) ----------------
__global__ __launch_bounds__(256) void convert_xw(const void* __restrict__ Xv,
                                                  const void* __restrict__ Wv,
                                                  unsigned short* __restrict__ Xb,
                                                  unsigned short* __restrict__ Wb)
{
  __shared__ int sx;
  const int tid = threadIdx.x, lane = tid & 63;
  if (tid == 0) sx = 0;
  __syncthreads();
  {
    unsigned xv = ((const unsigned*)Xv)[tid];
    unsigned b1 = (xv >> 8) & 0x7Fu;
    bool pb = (b1 >= 0x32u && b1 <= 0x41u);
    unsigned long long bal = __ballot(pb);
    if (lane == 0) atomicAdd(&sx, (int)__popcll(bal));
  }
  __syncthreads();
  const bool xbf = sx > 128;

  const size_t GX = (size_t)4096*1024/8;
  const size_t GT = GX + (size_t)3072*1024/8;
  for (size_t g = (size_t)blockIdx.x*256 + tid; g < GT; g += (size_t)gridDim.x*256) {
    const bool isX = g < GX;
    const size_t e = (isX ? g : g - GX) * 8;
    const void* src = isX ? Xv : Wv;
    unsigned short* dst = isX ? Xb : Wb;
    if (xbf) {
      *(uint4*)(dst + e) = *(const uint4*)((const unsigned short*)src + e);
    } else {
      float4 a = *(const float4*)((const float*)src + e);
      float4 b = *(const float4*)((const float*)src + e + 4);
      ushort4 u0{f2bf(a.x), f2bf(a.y), f2bf(a.z), f2bf(a.w)};
      ushort4 u1{f2bf(b.x), f2bf(b.y), f2bf(b.z), f2bf(b.w)};
      *(ushort4*)(dst + e)     = u0;
      *(ushort4*)(dst + e + 4) = u1;
    }
  }
}

// ---------------- QKV projection GEMM (pure m97) ----------------
__global__ __launch_bounds__(256) void qkv_gemm(const unsigned short* __restrict__ Xb,
                                                const unsigned short* __restrict__ Wb,
                                                unsigned short* __restrict__ Qg,
                                                unsigned short* __restrict__ Kg,
                                                unsigned short* __restrict__ Vt)
{
  __shared__ unsigned short lA[128*64];
  __shared__ unsigned short lB[128*64];
  const int tid  = threadIdx.x;
  const int wid  = tid >> 6,  lane = tid & 63;
  const int quad = lane >> 4, l16  = lane & 15;
  const int bm = blockIdx.x, bn = blockIdx.y;
  const int wM = (wid >> 1) * 64, wN = (wid & 1) * 64;

  floatx4 acc[4][4] = {};

  for (int kt = 0; kt < KDIM; kt += 64) {
    __syncthreads();
    #pragma unroll
    for (int p = 0; p < 4; ++p) {
      int chunk = p*256 + tid;
      int r = chunk >> 3, c = chunk & 7;
      gld_lds16(Xb + (size_t)(bm*128 + r)*KDIM + kt + c*8, lA + chunk*8);
    }
    #pragma unroll
    for (int p = 0; p < 4; ++p) {
      int chunk = p*256 + tid;
      int r = chunk >> 3, c = chunk & 7;
      gld_lds16(Wb + (size_t)(bn*128 + r)*KDIM + kt + c*8, lB + chunk*8);
    }
    __syncthreads();

    #pragma unroll
    for (int ks = 0; ks < 2; ++ks) {
      shortx8 af[4], bfr[4];
      #pragma unroll
      for (int mi = 0; mi < 4; ++mi)
        af[mi] = *(const shortx8*)(lA + (wM + mi*16 + l16)*64 + ks*32 + quad*8);
      #pragma unroll
      for (int ni = 0; ni < 4; ++ni)
        bfr[ni] = *(const shortx8*)(lB + (wN + ni*16 + l16)*64 + ks*32 + quad*8);
      #pragma unroll
      for (int mi = 0; mi < 4; ++mi)
        #pragma unroll
        for (int ni = 0; ni < 4; ++ni)
          acc[mi][ni] = __builtin_amdgcn_mfma_f32_16x16x32_bf16(af[mi], bfr[ni], acc[mi][ni], 0, 0, 0);
    }
  }

  if (bn < 8) {
    #pragma unroll
    for (int mi = 0; mi < 4; ++mi)
      #pragma unroll
      for (int ni = 0; ni < 4; ++ni)
        #pragma unroll
        for (int r = 0; r < 4; ++r) {
          int m = bm*128 + wM + mi*16 + quad*4 + r;
          int n = bn*128 + wN + ni*16 + l16;
          int b = m >> 11, q = m & 2047, h = n >> 6, d = n & 63;
          Qg[(((size_t)(b*NH_ + h))*S_ + q)*HD_ + d] = f2bf(acc[mi][ni][r] * 0.125f);
        }
  } else if (bn < 16) {
    #pragma unroll
    for (int mi = 0; mi < 4; ++mi)
      #pragma unroll
      for (int ni = 0; ni < 4; ++ni)
        #pragma unroll
        for (int r = 0; r < 4; ++r) {
          int m = bm*128 + wM + mi*16 + quad*4 + r;
          int n = bn*128 + wN + ni*16 + l16 - 1024;
          int b = m >> 11, t = m & 2047, h = n >> 6, d = n & 63;
          Kg[(((size_t)(b*NH_ + h))*S_ + t)*HD_ + d] = f2bf(acc[mi][ni][r]);
        }
  } else {
    #pragma unroll
    for (int mi = 0; mi < 4; ++mi)
      #pragma unroll
      for (int ni = 0; ni < 4; ++ni) {
        int m0 = bm*128 + wM + mi*16 + quad*4;
        int n  = bn*128 + wN + ni*16 + l16 - 2048;
        int b = m0 >> 11, t = m0 & 2047, h = n >> 6, d = n & 63;
        ushort4 u;
        u.x = f2bf(acc[mi][ni][0]); u.y = f2bf(acc[mi][ni][1]);
        u.z = f2bf(acc[mi][ni][2]); u.w = f2bf(acc[mi][ni][3]);
        *(ushort4*)(Vt + (((size_t)(b*NH_ + h))*HD_ + d)*S_ + t) = u;
      }
  }
}

// ---------------- fused masked flash attention: QB=64, 40 KB LDS, 4 blocks/CU ----------------
__global__ __launch_bounds__(256, 4) void attn_kernel(const unsigned short* __restrict__ Qg,
                                                      const unsigned short* __restrict__ Kg,
                                                      const unsigned short* __restrict__ Vt,
                                                      const void* __restrict__ maskp,
                                                      const void* __restrict__ xg,
                                                      void* __restrict__ outv)
{
  // exactly 40960 B -> 4 blocks/CU: P(8K) | K dbuf(16K) | V dbuf(16K)
  __shared__ unsigned short smem[20480];
  unsigned short* lP  = smem;                 // 4 waves x 16x64 (detection scratch aliased here)
  unsigned short* lK0 = smem + 4096;
  unsigned short* lV0 = smem + 12288;
  int* sdet = (int*)smem;                     // consumed right after first barrier, before P writes

  const int tid  = threadIdx.x;
  const int wid  = tid >> 6,  lane = tid & 63;
  const int quad = lane >> 4, l16  = lane & 15;
  const int qb = blockIdx.x * QB_;
  const int h  = blockIdx.y, b = blockIdx.z;
  const int bh = b*NH_ + h;

  if (tid < 3) sdet[tid] = (tid == 2) ? 0 : 1;
  __syncthreads();
  {
    unsigned mv = ((const unsigned*)maskp)[tid];
    bool w4 = (mv <= 1u) || (mv == 0x3F800000u);
    unsigned lo = mv & 0xFFFFu, hi = mv >> 16;
    bool w2 = ((lo==0u)||(lo==0x3F80u)) && ((hi==0u)||(hi==0x3F80u));
    unsigned xv = ((const unsigned*)xg)[tid];
    unsigned b1 = (xv >> 8) & 0x7Fu;
    bool pb = (b1 >= 0x32u && b1 <= 0x41u);
    unsigned long long B4 = __ballot(w4), B2 = __ballot(w2), BX = __ballot(pb);
    if (lane == 0) {
      if (~B4) atomicAnd(&sdet[0], 0);
      if (~B2) atomicAnd(&sdet[1], 0);
      atomicAdd(&sdet[2], (int)__popcll(BX));
    }
  }

  auto stage = [&](int t0, int buf) {
    unsigned short* k = lK0 + buf*4096;
    unsigned short* v = lV0 + buf*4096;
    #pragma unroll
    for (int p = 0; p < 2; ++p) {
      int chunk = p*256 + tid;
      gld_lds16(Kg + ((size_t)bh*S_ + t0)*HD_ + chunk*8, k + chunk*8);
    }
    #pragma unroll
    for (int p = 0; p < 2; ++p) {
      int chunk = p*256 + tid;
      int r = chunk >> 3, c = chunk & 7;
      gld_lds16(Vt + ((size_t)bh*HD_ + r)*S_ + t0 + c*8, v + chunk*8);
    }
  };

  size_t mrow[4];
  #pragma unroll
  for (int r = 0; r < 4; ++r) {
    int q = qb + wid*16 + quad*4 + r;
    mrow[r] = (((size_t)b*S_ + q)*NH_ + h)*S_ + l16;
  }

  // Q fragments straight from global (coalesced 16 B/lane) — no LDS staging
  shortx8 qf[2];
  {
    int q16 = qb + wid*16 + l16;
    #pragma unroll
    for (int ks = 0; ks < 2; ++ks)
      qf[ks] = *(const shortx8*)(Qg + ((size_t)bh*S_ + q16)*HD_ + ks*32 + quad*8);
  }

  stage(0, 0);
  __syncthreads();                 // detection + tile0 staging drained
  const int esz = sdet[0] ? 4 : (sdet[1] ? 2 : 1);
  const int obf = sdet[2] > 128;

  auto loadraw = [&](int t0, unsigned (*mz)[4]) {
    if (esz == 4) {
      const unsigned* mp = (const unsigned*)maskp;
      #pragma unroll
      for (int r = 0; r < 4; ++r)
        #pragma unroll
        for (int tile = 0; tile < 4; ++tile) mz[r][tile] = mp[mrow[r] + t0 + tile*16];
    } else if (esz == 2) {
      const unsigned short* mp = (const unsigned short*)maskp;
      #pragma unroll
      for (int r = 0; r < 4; ++r)
        #pragma unroll
        for (int tile = 0; tile < 4; ++tile) mz[r][tile] = mp[mrow[r] + t0 + tile*16];
    } else {
      const unsigned char* mp = (const unsigned char*)maskp;
      #pragma unroll
      for (int r = 0; r < 4; ++r)
        #pragma unroll
        for (int tile = 0; tile < 4; ++tile) mz[r][tile] = mp[mrow[r] + t0 + tile*16];
    }
  };

  floatx4 acc[4] = {};
  float lsum[4] = {};
  unsigned short* lPw = lP + wid*1024;   // this wave's 16x64 P region

  unsigned mc = 0;
  {
    unsigned m0[4][4];
    loadraw(0, m0);
    #pragma unroll
    for (int r = 0; r < 4; ++r)
      #pragma unroll
      for (int tile = 0; tile < 4; ++tile)
        mc |= (m0[r][tile] != 0u ? 1u : 0u) << (r*4 + tile);
  }

  for (int t0 = 0; t0 < S_; t0 += 64) {
    const int cur = (t0 >> 6) & 1;
    unsigned mraw[4][4];
    const bool more = (t0 + 64 < S_);
    if (more) {
      stage(t0 + 64, cur ^ 1);
      loadraw(t0 + 64, mraw);
    }
    const unsigned short* k = lK0 + cur*4096;
    const unsigned short* v = lV0 + cur*4096;

    // S = Q K^T (Q pre-scaled)
    floatx4 sc[4] = {};
    #pragma unroll
    for (int tile = 0; tile < 4; ++tile)
      #pragma unroll
      for (int ks = 0; ks < 2; ++ks) {
        shortx8 kf = *(const shortx8*)(k + (tile*16 + l16)*64 + ks*32 + quad*8);
        sc[tile] = __builtin_amdgcn_mfma_f32_16x16x32_bf16(qf[ks], kf, sc[tile], 0, 0, 0);
      }

    // max-free masked softmax; P into per-wave LDS (xor-swizzled)
    #pragma unroll
    for (int r = 0; r < 4; ++r)
      #pragma unroll
      for (int tile = 0; tile < 4; ++tile) {
        float e = __expf(sc[tile][r]);
        e = (mc & (1u << (r*4 + tile))) ? e : 0.f;
        lsum[r] += e;
        int row = quad*4 + r;
        int col = tile*16 + l16;
        lPw[(row << 6) + (((col >> 3) ^ (row & 7)) << 3) + (col & 7)] = f2bf(e);
      }

    // P·V
    #pragma unroll
    for (int ks = 0; ks < 2; ++ks) {
      shortx8 pa = *(const shortx8*)(lPw + (l16 << 6) + (((ks*4 + quad) ^ (l16 & 7)) << 3));
      #pragma unroll
      for (int d = 0; d < 4; ++d) {
        shortx8 vb = *(const shortx8*)(v + (d*16 + l16)*64 + ks*32 + quad*8);
        acc[d] = __builtin_amdgcn_mfma_f32_16x16x32_bf16(pa, vb, acc[d], 0, 0, 0);
      }
    }

    unsigned mcn = 0;
    if (more) {
      #pragma unroll
      for (int r = 0; r < 4; ++r)
        #pragma unroll
        for (int tile = 0; tile < 4; ++tile)
          mcn |= (mraw[r][tile] != 0u ? 1u : 0u) << (r*4 + tile);
    }
    __syncthreads();   // drains next-tile staging (a full compute phase old)
    mc = mcn;
  }

  float rinv[4];
  #pragma unroll
  for (int r = 0; r < 4; ++r) {
    float l = lsum[r];
    #pragma unroll
    for (int o = 1; o < 16; o <<= 1) l += __shfl_xor(l, o);
    rinv[r] = 1.f / l;
  }

  #pragma unroll
  for (int d = 0; d < 4; ++d)
    #pragma unroll
    for (int r = 0; r < 4; ++r) {
      int q = qb + wid*16 + quad*4 + r;
      size_t oi = ((size_t)b*S_ + q)*DM_ + h*HD_ + d*16 + l16;
      float v = acc[d][r] * rinv[r];
      if (obf) ((unsigned short*)outv)[oi] = f2bf(v);
      else     ((float*)outv)[oi]          = v;
    }
}

extern "C" void kernel_launch(void* const* d_in, const int* in_sizes, int n_in,
                              void* d_out, int out_size, void* d_ws, size_t ws_size,
                              hipStream_t stream) {
  (void)in_sizes; (void)n_in; (void)out_size; (void)ws_size;
  const void* X    = d_in[0];
  const void* W    = d_in[1];
  const void* mask = d_in[2];
  const size_t SEG = (size_t)2*NH_*S_*HD_*2;  // 8.39 MB per Q/K/V tensor
  unsigned short* Qg = (unsigned short*)((char*)d_ws + 256);
  unsigned short* Kg = (unsigned short*)((char*)d_ws + 256 + SEG);
  unsigned short* Vt = (unsigned short*)((char*)d_ws + 256 + 2*SEG);
  unsigned short* Xb = (unsigned short*)((char*)d_ws + 256 + 3*SEG);   // 8.39 MB
  unsigned short* Wb = Xb + (size_t)4096*1024;                          // 6.29 MB

  convert_xw<<<512, 256, 0, stream>>>(X, W, Xb, Wb);
  qkv_gemm<<<dim3(32, 24), 256, 0, stream>>>(Xb, Wb, Qg, Kg, Vt);
  attn_kernel<<<dim3(S_/QB_, NH_, 2), 256, 0, stream>>>(Qg, Kg, Vt, mask, X, d_out);
}